// Round 1
// baseline (233.620 us; speedup 1.0000x reference)
//
#include <hip/hip_runtime.h>

typedef unsigned short u16;
typedef __attribute__((ext_vector_type(8))) short s16x8;
typedef __attribute__((ext_vector_type(4))) float f32x4;
typedef __attribute__((ext_vector_type(4))) u16 u16x4;

#define SLEN 2048
#define DMODEL 1024
#define NHEAD 16
#define DHEAD 64
#define LDQKV 3072

__device__ __forceinline__ u16 f2bf(float f) {
  unsigned u = __float_as_uint(f);
  u = (u + 0x7FFFu + ((u >> 16) & 1u)) >> 16;
  return (u16)u;
}

__device__ __forceinline__ void gload_lds16(const u16* gsrc, u16* lds) {
  __builtin_amdgcn_global_load_lds((const __attribute__((address_space(1))) void*)gsrc,
                                   (__attribute__((address_space(3))) void*)lds, 16, 0, 0);
}

// ---------------- weight convert: fp32 -> bf16, concat qkv ----------------
__global__ __launch_bounds__(256) void convert_w_kernel(
    const float* __restrict__ Wq, const float* __restrict__ Wk, const float* __restrict__ Wv,
    const float* __restrict__ Wo, const float* __restrict__ bq, const float* __restrict__ bk,
    const float* __restrict__ bv, u16* __restrict__ Wqkv, u16* __restrict__ Wob,
    float* __restrict__ bias_qkv) {
  const int t = blockIdx.x * 256 + threadIdx.x;
  float4 v;
  u16* dst;
  if (t < 786432) {                      // 3*1024*1024/4 qkv weight float4s
    const int idx = t * 4;
    const int sec = idx >> 20;
    const int off = idx & 1048575;
    const float* src = (sec == 0) ? Wq : (sec == 1) ? Wk : Wv;
    v = *(const float4*)(src + off);
    dst = Wqkv + idx;
  } else {
    const int idx = (t - 786432) * 4;    // Wo: 1M elems
    v = *(const float4*)(Wo + idx);
    dst = Wob + idx;
  }
  u16x4 o = { f2bf(v.x), f2bf(v.y), f2bf(v.z), f2bf(v.w) };
  *(u16x4*)dst = o;
  if (t < 768) {                          // bias concat 3072 floats
    const int idx = t * 4;
    const int sec = idx >> 10;
    const int off = idx & 1023;
    const float* src = (sec == 0) ? bq : (sec == 1) ? bk : bv;
    *(float4*)(bias_qkv + idx) = *(const float4*)(src + off);
  }
}

// ---------------- LayerNorm (optionally fused residual add) ----------------
template <bool RES>
__global__ __launch_bounds__(256) void ln_kernel(
    const float* __restrict__ xa, const float* __restrict__ xb,
    const float* __restrict__ g, const float* __restrict__ bb,
    u16* __restrict__ outb, float* __restrict__ resout) {
  const int row = blockIdx.x, t = threadIdx.x;
  const size_t base = (size_t)row * DMODEL;
  float4 v = *((const float4*)(xa + base) + t);
  if (RES) {
    float4 u = *((const float4*)(xb + base) + t);
    v.x += u.x; v.y += u.y; v.z += u.z; v.w += u.w;
    *((float4*)(resout + base) + t) = v;
  }
  float s1 = v.x + v.y + v.z + v.w;
  float s2 = v.x * v.x + v.y * v.y + v.z * v.z + v.w * v.w;
#pragma unroll
  for (int d = 1; d < 64; d <<= 1) { s1 += __shfl_xor(s1, d); s2 += __shfl_xor(s2, d); }
  __shared__ float red[8];
  if ((t & 63) == 0) { red[(t >> 6) * 2] = s1; red[(t >> 6) * 2 + 1] = s2; }
  __syncthreads();
  s1 = red[0] + red[2] + red[4] + red[6];
  s2 = red[1] + red[3] + red[5] + red[7];
  const float mu = s1 * (1.0f / 1024.0f);
  const float var = s2 * (1.0f / 1024.0f) - mu * mu;
  const float rs = rsqrtf(var + 1e-6f);
  const int c = t * 4;
  float o0 = (v.x - mu) * rs * g[c + 0] + bb[c + 0];
  float o1 = (v.y - mu) * rs * g[c + 1] + bb[c + 1];
  float o2 = (v.z - mu) * rs * g[c + 2] + bb[c + 2];
  float o3 = (v.w - mu) * rs * g[c + 3] + bb[c + 3];
  u16x4 o = { f2bf(o0), f2bf(o1), f2bf(o2), f2bf(o3) };
  *((u16x4*)(outb + base) + t) = o;
}

// ---------------- bf16 GEMM: C[M,N] = A[M,K] * B[N,K]^T + bias (+res) ----------------
// OUTMODE 0: bf16 out.  OUTMODE 1: fp32 out with residual add.
template <int OUTMODE>
__global__ __launch_bounds__(256) void gemm_bt_kernel(
    const u16* __restrict__ A, const u16* __restrict__ B,
    const float* __restrict__ bias, const float* __restrict__ res,
    u16* __restrict__ outb, float* __restrict__ outf,
    int M, int N, int K) {
  __shared__ __align__(16) u16 As[128 * 64];
  __shared__ __align__(16) u16 Bs[128 * 64];
  const int t = threadIdx.x;
  const int l = t & 63, w = t >> 6, lr = l & 15, lg = l >> 4;
  const int wm = w >> 1, wn = w & 1;
  const int m0 = blockIdx.x * 128, n0 = blockIdx.y * 128;

  const f32x4 z4 = {0.f, 0.f, 0.f, 0.f};
  f32x4 acc[4][4];
#pragma unroll
  for (int i = 0; i < 4; ++i)
#pragma unroll
    for (int j = 0; j < 4; ++j) acc[i][j] = z4;

  for (int kt = 0; kt < K; kt += 64) {
    // stage 128x64 A and B tiles; LDS dest linear, global source pre-swizzled
#pragma unroll
    for (int p = 0; p < 4; ++p) {
      const int idx = p * 256 + t;            // 16B chunk id, 0..1023
      const int row = idx >> 3;
      const int blk = idx & 7;
      const int sb = blk ^ (row & 7);
      gload_lds16(A + (size_t)(m0 + row) * K + kt + sb * 8, &As[idx * 8]);
      gload_lds16(B + (size_t)(n0 + row) * K + kt + sb * 8, &Bs[idx * 8]);
    }
    asm volatile("s_waitcnt vmcnt(0)" ::: "memory");
    __syncthreads();

#pragma unroll
    for (int ks = 0; ks < 2; ++ks) {
      s16x8 af[4], bfr[4];
#pragma unroll
      for (int mi = 0; mi < 4; ++mi) {
        const int row = wm * 64 + mi * 16 + lr;
        af[mi] = *(const s16x8*)&As[row * 64 + (((ks * 4 + lg) ^ (row & 7)) & 7) * 8];
      }
#pragma unroll
      for (int ni = 0; ni < 4; ++ni) {
        const int row = wn * 64 + ni * 16 + lr;
        bfr[ni] = *(const s16x8*)&Bs[row * 64 + (((ks * 4 + lg) ^ (row & 7)) & 7) * 8];
      }
#pragma unroll
      for (int mi = 0; mi < 4; ++mi)
#pragma unroll
        for (int ni = 0; ni < 4; ++ni)
          acc[mi][ni] = __builtin_amdgcn_mfma_f32_16x16x32_bf16(af[mi], bfr[ni], acc[mi][ni], 0, 0, 0);
    }
    __syncthreads();
  }

#pragma unroll
  for (int mi = 0; mi < 4; ++mi)
#pragma unroll
    for (int ni = 0; ni < 4; ++ni) {
      const int col = n0 + wn * 64 + ni * 16 + lr;
#pragma unroll
      for (int r = 0; r < 4; ++r) {
        const int rowb = m0 + wm * 64 + mi * 16 + lg * 4 + r;
        float vv = acc[mi][ni][r] + bias[col];
        if (OUTMODE == 0) {
          outb[(size_t)rowb * N + col] = f2bf(vv);
        } else {
          vv += res[(size_t)rowb * N + col];
          outf[(size_t)rowb * N + col] = vv;
        }
      }
    }
}

// ---------------- flash attention ----------------
// grid: (S/64, H, B); block 256 = 4 waves, each wave owns 16 q rows.
__global__ __launch_bounds__(256) void attn_kernel(
    const u16* __restrict__ qkv, const float* __restrict__ mask, float* __restrict__ out) {
  const int b = blockIdx.z, h = blockIdx.y, q0 = blockIdx.x * 64;
  const int t = threadIdx.x;
  const int l = t & 63, w = t >> 6, lr = l & 15, lg = l >> 4;

  __shared__ __align__(16) u16 Qs[64 * 64];
  __shared__ __align__(16) u16 Ks[64 * 64];
  __shared__ __align__(16) u16 Vs[64 * 64];   // V^T, triple-XOR swizzled
  __shared__ __align__(16) u16 Ps[4][16 * 72];

  const size_t rowbase = (size_t)b * SLEN * LDQKV;
  const u16* qptr = qkv + rowbase + (size_t)q0 * LDQKV + h * DHEAD;
  const u16* kptr = qkv + rowbase + DMODEL + h * DHEAD;
  const u16* vptr = qkv + rowbase + 2 * DMODEL + h * DHEAD;

  // stage Q tile (simple XOR swizzle: data of block (blk^(row&7)) stored at blk)
#pragma unroll
  for (int p = 0; p < 2; ++p) {
    const int idx = p * 256 + t;
    const int row = idx >> 3;
    const int blk = idx & 7;
    const int sb = blk ^ (row & 7);
    s16x8 v = *(const s16x8*)(qptr + (size_t)row * LDQKV + sb * 8);
    *(s16x8*)&Qs[row * 64 + blk * 8] = v;
  }

  const f32x4 z4 = {0.f, 0.f, 0.f, 0.f};
  f32x4 accO[4] = {z4, z4, z4, z4};
  float mrun[4], lsum[4];
#pragma unroll
  for (int r = 0; r < 4; ++r) { mrun[r] = -3.0e38f; lsum[r] = 0.f; }

  __syncthreads();

  for (int kv0 = 0; kv0 < SLEN; kv0 += 64) {
    // stage K (same layout as Q)
#pragma unroll
    for (int p = 0; p < 2; ++p) {
      const int idx = p * 256 + t;
      const int row = idx >> 3;
      const int blk = idx & 7;
      const int sb = blk ^ (row & 7);
      s16x8 v = *(const s16x8*)(kptr + (size_t)(kv0 + row) * LDQKV + sb * 8);
      *(s16x8*)&Ks[row * 64 + blk * 8] = v;
    }
    // stage V^T: Vs[dh][kv] with block swizzle (kv>>3)^(dh&7)^((dh>>3)&7)
#pragma unroll
    for (int p = 0; p < 2; ++p) {
      const int kv = w * 8 + (l >> 3) + p * 32;
      const int dh0 = (l & 7) * 8;
      s16x8 v = *(const s16x8*)(vptr + (size_t)(kv0 + kv) * LDQKV + dh0);
      u16 tmp[8];
      *(s16x8*)tmp = v;
#pragma unroll
      for (int j = 0; j < 8; ++j) {
        const int dh = dh0 + j;
        const int blk2 = ((kv >> 3) ^ (dh & 7) ^ ((dh >> 3) & 7)) & 7;
        Vs[dh * 64 + blk2 * 8 + (kv & 7)] = tmp[j];
      }
    }
    __syncthreads();

    // ---- S = Q K^T (wave strip: 16 q rows x 64 kv) ----
    f32x4 s[4] = {z4, z4, z4, z4};
#pragma unroll
    for (int ks = 0; ks < 2; ++ks) {
      const int qrow = w * 16 + lr;
      s16x8 aq = *(const s16x8*)&Qs[qrow * 64 + (((ks * 4 + lg) ^ (qrow & 7)) & 7) * 8];
#pragma unroll
      for (int nn = 0; nn < 4; ++nn) {
        const int krow = nn * 16 + lr;
        s16x8 bk = *(const s16x8*)&Ks[krow * 64 + (((ks * 4 + lg) ^ (krow & 7)) & 7) * 8];
        s[nn] = __builtin_amdgcn_mfma_f32_16x16x32_bf16(aq, bk, s[nn], 0, 0, 0);
      }
    }

    // ---- scale + mask + online softmax ----
    float mkv[4];
#pragma unroll
    for (int nn = 0; nn < 4; ++nn)
      mkv[nn] = (1.0f - mask[b * SLEN + kv0 + nn * 16 + lr]) * -1e30f;
#pragma unroll
    for (int nn = 0; nn < 4; ++nn)
#pragma unroll
      for (int r = 0; r < 4; ++r) s[nn][r] = s[nn][r] * 0.125f + mkv[nn];

    float p_[4][4];
#pragma unroll
    for (int r = 0; r < 4; ++r) {
      float mx = fmaxf(fmaxf(s[0][r], s[1][r]), fmaxf(s[2][r], s[3][r]));
      mx = fmaxf(mx, __shfl_xor(mx, 1));
      mx = fmaxf(mx, __shfl_xor(mx, 2));
      mx = fmaxf(mx, __shfl_xor(mx, 4));
      mx = fmaxf(mx, __shfl_xor(mx, 8));
      const float mn = fmaxf(mrun[r], mx);
      const float alpha = __expf(mrun[r] - mn);
      mrun[r] = mn;
      float rsum = 0.f;
#pragma unroll
      for (int nn = 0; nn < 4; ++nn) {
        const float pv = __expf(s[nn][r] - mn);
        p_[nn][r] = pv;
        rsum += pv;
      }
      rsum += __shfl_xor(rsum, 1);
      rsum += __shfl_xor(rsum, 2);
      rsum += __shfl_xor(rsum, 4);
      rsum += __shfl_xor(rsum, 8);
      lsum[r] = lsum[r] * alpha + rsum;
#pragma unroll
      for (int nn = 0; nn < 4; ++nn) accO[nn][r] *= alpha;
    }

    // ---- write P to per-wave LDS (D-layout -> A-layout transpose) ----
#pragma unroll
    for (int nn = 0; nn < 4; ++nn)
#pragma unroll
      for (int r = 0; r < 4; ++r)
        Ps[w][(lg * 4 + r) * 72 + nn * 16 + lr] = f2bf(p_[nn][r]);

    // ---- O += P V ----
#pragma unroll
    for (int ks = 0; ks < 2; ++ks) {
      s16x8 ap = *(const s16x8*)&Ps[w][lr * 72 + ks * 32 + lg * 8];
#pragma unroll
      for (int nn = 0; nn < 4; ++nn) {
        const int dh = nn * 16 + lr;
        const int blkv = (((ks * 4 + lg) ^ (dh & 7) ^ ((dh >> 3) & 7)) & 7);
        s16x8 bv = *(const s16x8*)&Vs[dh * 64 + blkv * 8];
        accO[nn] = __builtin_amdgcn_mfma_f32_16x16x32_bf16(ap, bv, accO[nn], 0, 0, 0);
      }
    }
    __syncthreads();
  }

  // epilogue: out[b][q][h*64+dh] = O / l
  float* orow = out + ((size_t)b * SLEN + q0 + w * 16) * DMODEL + h * DHEAD;
#pragma unroll
  for (int nn = 0; nn < 4; ++nn)
#pragma unroll
    for (int r = 0; r < 4; ++r) {
      const int qr = lg * 4 + r;
      const int dh = nn * 16 + lr;
      orow[(size_t)qr * DMODEL + dh] = accO[nn][r] / lsum[r];
    }
}

extern "C" void kernel_launch(void* const* d_in, const int* in_sizes, int n_in,
                              void* d_out, int out_size, void* d_ws, size_t ws_size,
                              hipStream_t stream) {
  const float* x    = (const float*)d_in[0];
  const float* mask = (const float*)d_in[1];
  const float* Wq   = (const float*)d_in[2];
  const float* bq   = (const float*)d_in[3];
  const float* Wk   = (const float*)d_in[4];
  const float* bk   = (const float*)d_in[5];
  const float* Wv   = (const float*)d_in[6];
  const float* bv   = (const float*)d_in[7];
  const float* Wo   = (const float*)d_in[8];
  const float* bo   = (const float*)d_in[9];
  const float* g1   = (const float*)d_in[10];
  const float* b1   = (const float*)d_in[11];
  const float* g2   = (const float*)d_in[12];
  const float* b2   = (const float*)d_in[13];
  float* out = (float*)d_out;
  char* ws = (char*)d_ws;

  u16*   h_bf  = (u16*)(ws + 0);                       // 8 MB  (later reused as h2)
  u16*   Wqkv  = (u16*)(ws + ((size_t)8 << 20));       // 6 MB
  u16*   Wob   = (u16*)(ws + ((size_t)14 << 20));      // 2 MB
  float* biasq = (float*)(ws + ((size_t)16 << 20));    // 12 KB
  u16*   qkv   = (u16*)(ws + ((size_t)17 << 20));      // 24 MB (later reused as resid)
  float* attn  = (float*)(ws + ((size_t)41 << 20));    // 16 MB
  float* resid = (float*)(ws + ((size_t)17 << 20));    // overlays dead qkv
  u16*   h2_bf = (u16*)(ws + 0);                       // overlays dead h_bf

  convert_w_kernel<<<4096, 256, 0, stream>>>(Wq, Wk, Wv, Wo, bq, bk, bv, Wqkv, Wob, biasq);
  ln_kernel<false><<<4096, 256, 0, stream>>>(x, nullptr, g1, b1, h_bf, nullptr);
  gemm_bt_kernel<0><<<dim3(32, 24), 256, 0, stream>>>(h_bf, Wqkv, biasq, nullptr, qkv, nullptr,
                                                      4096, 3072, 1024);
  attn_kernel<<<dim3(32, 16, 2), 256, 0, stream>>>(qkv, mask, attn);
  ln_kernel<true><<<4096, 256, 0, stream>>>(attn, x, g2, b2, h2_bf, resid);
  gemm_bt_kernel<1><<<dim3(32, 8), 256, 0, stream>>>(h2_bf, Wob, bo, resid, nullptr, out,
                                                     4096, 1024, 1024);
}

// Round 4
// 178.002 us; speedup vs baseline: 1.3125x; 1.3125x over previous
//
#include <hip/hip_runtime.h>

typedef unsigned short u16;
typedef unsigned int u32;
typedef __attribute__((ext_vector_type(8))) short s16x8;
typedef __attribute__((ext_vector_type(4))) float f32x4;
typedef __attribute__((ext_vector_type(16))) float f32x16;
typedef __attribute__((ext_vector_type(4))) u16 u16x4;

#define SLEN 2048
#define DMODEL 1024
#define NHEAD 16
#define DHEAD 64
#define LDQKV 3072

__device__ __forceinline__ u16 f2bf(float f) {
  unsigned u = __float_as_uint(f);
  u = (u + 0x7FFFu + ((u >> 16) & 1u)) >> 16;
  return (u16)u;
}

__device__ __forceinline__ u32 pk2(float a, float b) {
  return (u32)f2bf(a) | ((u32)f2bf(b) << 16);
}

__device__ __forceinline__ void gload_lds16(const u16* gsrc, u16* lds) {
  __builtin_amdgcn_global_load_lds((const __attribute__((address_space(1))) void*)gsrc,
                                   (__attribute__((address_space(3))) void*)lds, 16, 0, 0);
}

// Build PV A-fragment from 8 P values (this lane: q = l31, kv rids
// {4hi..4hi+3, 8+4hi..8+4hi+3} within a 16-kv slice). Direction-proof
// half-exchange via shfl_xor(32): lane needs kv {8hi + 0..7}.
__device__ __forceinline__ s16x8 make_pa(int hi, const float* p) {
  u32 A0 = pk2(p[0], p[1]), A1 = pk2(p[2], p[3]);
  u32 A2 = pk2(p[4], p[5]), A3 = pk2(p[6], p[7]);
  u32 B0 = (u32)__shfl_xor((int)A0, 32);
  u32 B1 = (u32)__shfl_xor((int)A1, 32);
  u32 B2 = (u32)__shfl_xor((int)A2, 32);
  u32 B3 = (u32)__shfl_xor((int)A3, 32);
  union { u32 w[4]; s16x8 v; } pw;
  pw.w[0] = hi ? B2 : A0;   // kv {8hi+0, 8hi+1}
  pw.w[1] = hi ? B3 : A1;   // kv {8hi+2, 8hi+3}
  pw.w[2] = hi ? A2 : B0;   // kv {8hi+4, 8hi+5}
  pw.w[3] = hi ? A3 : B1;   // kv {8hi+6, 8hi+7}
  return pw.v;
}

// ---------------- weight convert: fp32 -> bf16, concat qkv, additive mask ----------------
__global__ __launch_bounds__(256) void convert_w_kernel(
    const float* __restrict__ Wq, const float* __restrict__ Wk, const float* __restrict__ Wv,
    const float* __restrict__ Wo, const float* __restrict__ bq, const float* __restrict__ bk,
    const float* __restrict__ bv, const float* __restrict__ mask,
    u16* __restrict__ Wqkv, u16* __restrict__ Wob, float* __restrict__ bias_qkv,
    float* __restrict__ am) {
  const int t = blockIdx.x * 256 + threadIdx.x;
  float4 v;
  u16* dst;
  if (t < 786432) {
    const int idx = t * 4;
    const int sec = idx >> 20;
    const int off = idx & 1048575;
    const float* src = (sec == 0) ? Wq : (sec == 1) ? Wk : Wv;
    v = *(const float4*)(src + off);
    dst = Wqkv + idx;
  } else {
    const int idx = (t - 786432) * 4;
    v = *(const float4*)(Wo + idx);
    dst = Wob + idx;
  }
  u16x4 o = { f2bf(v.x), f2bf(v.y), f2bf(v.z), f2bf(v.w) };
  *(u16x4*)dst = o;
  if (t < 768) {
    const int idx = t * 4;
    const int sec = idx >> 10;
    const int off = idx & 1023;
    const float* src = (sec == 0) ? bq : (sec == 1) ? bk : bv;
    *(float4*)(bias_qkv + idx) = *(const float4*)(src + off);
  }
  if (t < 1024) {                        // additive mask, B*S = 4096 floats
    const int idx = t * 4;
    float4 mk = *(const float4*)(mask + idx);
    float4 o2 = { (1.f - mk.x) * -1e30f, (1.f - mk.y) * -1e30f,
                  (1.f - mk.z) * -1e30f, (1.f - mk.w) * -1e30f };
    *(float4*)(am + idx) = o2;
  }
}

// ---------------- LayerNorm (optionally fused residual add) ----------------
template <bool RES>
__global__ __launch_bounds__(256) void ln_kernel(
    const float* __restrict__ xa, const float* __restrict__ xb,
    const float* __restrict__ g, const float* __restrict__ bb,
    u16* __restrict__ outb, float* __restrict__ resout) {
  const int row = blockIdx.x, t = threadIdx.x;
  const size_t base = (size_t)row * DMODEL;
  float4 v = *((const float4*)(xa + base) + t);
  if (RES) {
    float4 u = *((const float4*)(xb + base) + t);
    v.x += u.x; v.y += u.y; v.z += u.z; v.w += u.w;
    *((float4*)(resout + base) + t) = v;
  }
  float s1 = v.x + v.y + v.z + v.w;
  float s2 = v.x * v.x + v.y * v.y + v.z * v.z + v.w * v.w;
#pragma unroll
  for (int d = 1; d < 64; d <<= 1) { s1 += __shfl_xor(s1, d); s2 += __shfl_xor(s2, d); }
  __shared__ float red[8];
  if ((t & 63) == 0) { red[(t >> 6) * 2] = s1; red[(t >> 6) * 2 + 1] = s2; }
  __syncthreads();
  s1 = red[0] + red[2] + red[4] + red[6];
  s2 = red[1] + red[3] + red[5] + red[7];
  const float mu = s1 * (1.0f / 1024.0f);
  const float var = s2 * (1.0f / 1024.0f) - mu * mu;
  const float rs = rsqrtf(var + 1e-6f);
  const int c = t * 4;
  float o0 = (v.x - mu) * rs * g[c + 0] + bb[c + 0];
  float o1 = (v.y - mu) * rs * g[c + 1] + bb[c + 1];
  float o2 = (v.z - mu) * rs * g[c + 2] + bb[c + 2];
  float o3 = (v.w - mu) * rs * g[c + 3] + bb[c + 3];
  u16x4 o = { f2bf(o0), f2bf(o1), f2bf(o2), f2bf(o3) };
  *((u16x4*)(outb + base) + t) = o;
}

// ---------------- bf16 GEMM: C[M,N] = A[M,K] * B[N,K]^T + bias (+res) ----------------
// OUTMODE 0: bf16 out, cols<1024 (Q) scaled by 1/8.  OUTMODE 1: fp32 out + residual.
template <int OUTMODE>
__global__ __launch_bounds__(256) void gemm_bt_kernel(
    const u16* __restrict__ A, const u16* __restrict__ B,
    const float* __restrict__ bias, const float* __restrict__ res,
    u16* __restrict__ outb, float* __restrict__ outf,
    int M, int N, int K) {
  __shared__ __align__(16) u16 As[128 * 64];
  __shared__ __align__(16) u16 Bs[128 * 64];
  const int t = threadIdx.x;
  const int l = t & 63, w = t >> 6, lr = l & 15, lg = l >> 4;
  const int wm = w >> 1, wn = w & 1;
  const int m0 = blockIdx.x * 128, n0 = blockIdx.y * 128;

  const f32x4 z4 = {0.f, 0.f, 0.f, 0.f};
  f32x4 acc[4][4];
#pragma unroll
  for (int i = 0; i < 4; ++i)
#pragma unroll
    for (int j = 0; j < 4; ++j) acc[i][j] = z4;

  for (int kt = 0; kt < K; kt += 64) {
#pragma unroll
    for (int p = 0; p < 4; ++p) {
      const int idx = p * 256 + t;
      const int row = idx >> 3;
      const int blk = idx & 7;
      const int sb = blk ^ (row & 7);
      gload_lds16(A + (size_t)(m0 + row) * K + kt + sb * 8, &As[idx * 8]);
      gload_lds16(B + (size_t)(n0 + row) * K + kt + sb * 8, &Bs[idx * 8]);
    }
    asm volatile("s_waitcnt vmcnt(0)" ::: "memory");
    __syncthreads();

#pragma unroll
    for (int ks = 0; ks < 2; ++ks) {
      s16x8 af[4], bfr[4];
#pragma unroll
      for (int mi = 0; mi < 4; ++mi) {
        const int row = wm * 64 + mi * 16 + lr;
        af[mi] = *(const s16x8*)&As[row * 64 + (((ks * 4 + lg) ^ (row & 7)) & 7) * 8];
      }
#pragma unroll
      for (int ni = 0; ni < 4; ++ni) {
        const int row = wn * 64 + ni * 16 + lr;
        bfr[ni] = *(const s16x8*)&Bs[row * 64 + (((ks * 4 + lg) ^ (row & 7)) & 7) * 8];
      }
#pragma unroll
      for (int mi = 0; mi < 4; ++mi)
#pragma unroll
        for (int ni = 0; ni < 4; ++ni)
          acc[mi][ni] = __builtin_amdgcn_mfma_f32_16x16x32_bf16(af[mi], bfr[ni], acc[mi][ni], 0, 0, 0);
    }
    __syncthreads();
  }

#pragma unroll
  for (int mi = 0; mi < 4; ++mi)
#pragma unroll
    for (int ni = 0; ni < 4; ++ni) {
      const int col = n0 + wn * 64 + ni * 16 + lr;
#pragma unroll
      for (int r = 0; r < 4; ++r) {
        const int rowb = m0 + wm * 64 + mi * 16 + lg * 4 + r;
        float vv = acc[mi][ni][r] + bias[col];
        if (OUTMODE == 0) {
          if (col < 1024) vv *= 0.125f;          // fold 1/sqrt(DH) into Q
          outb[(size_t)rowb * N + col] = f2bf(vv);
        } else {
          vv += res[(size_t)rowb * N + col];
          outf[(size_t)rowb * N + col] = vv;
        }
      }
    }
}

// ---------------- V transpose: vT[b][h][dh][s] = V[b][s][h*64+dh] ----------------
__global__ __launch_bounds__(256) void transpose_v_kernel(
    const u16* __restrict__ qkv, u16* __restrict__ vT) {
  const int s0 = blockIdx.x * 64, h = blockIdx.y, b = blockIdx.z;
  const int t = threadIdx.x;
  __shared__ u16 lds[64][72];
  const u16* src = qkv + (size_t)(b * SLEN + s0) * LDQKV + 2 * DMODEL + h * DHEAD;
#pragma unroll
  for (int p = 0; p < 2; ++p) {
    const int idx = p * 256 + t;
    const int s = idx >> 3, c = idx & 7;
    *(s16x8*)&lds[s][c * 8] = *(const s16x8*)(src + (size_t)s * LDQKV + c * 8);
  }
  __syncthreads();
  u16* dst = vT + (size_t)((b * NHEAD + h) * DHEAD) * SLEN + s0;
#pragma unroll
  for (int p = 0; p < 2; ++p) {
    const int idx = p * 256 + t;
    const int dh = idx >> 3, sp = idx & 7;
    s16x8 vv;
#pragma unroll
    for (int i = 0; i < 8; ++i) vv[i] = (short)lds[sp * 8 + i][dh];
    *(s16x8*)(dst + (size_t)dh * SLEN + sp * 8) = vv;
  }
}

// ---------------- flash attention, swapped-operand 32x32 MFMA ----------------
// grid: 512 blocks x 256 thr (4 waves); wave owns 32 q rows; KV tile = 64.
__global__ __launch_bounds__(256) void attn_kernel(
    const u16* __restrict__ qkv, const u16* __restrict__ vT,
    const float* __restrict__ am, float* __restrict__ out) {
  const int did = blockIdx.x;
  const int lid = (did & 7) * 64 + (did >> 3);   // XCD-chunked (512 % 8 == 0)
  const int qb = lid & 15;
  const int h = (lid >> 4) & 15;
  const int b = lid >> 8;

  const int t = threadIdx.x;
  const int l = t & 63, w = t >> 6;
  const int l31 = l & 31;
  const int hi = l >> 5;
  const int hi4 = hi * 4;
  const int sw = l31 & 7;                        // row-swizzle key

  __shared__ __align__(16) u16 Ks[2][64 * 64];
  __shared__ __align__(16) u16 Vs[2][64 * 64];
  __shared__ float amS[SLEN];
  __shared__ float bcastS[4][32];

  const int q0 = qb * 128 + w * 32;

  // Q fragments direct from global (already scaled by 1/8)
  const u16* qrow = qkv + (size_t)(b * SLEN + q0 + l31) * LDQKV + h * DHEAD + hi * 8;
  s16x8 qf[4];
#pragma unroll
  for (int f = 0; f < 4; ++f) qf[f] = *(const s16x8*)(qrow + f * 16);

  // stage additive mask for this batch
  {
    const float4* srcm = (const float4*)(am + b * SLEN);
#pragma unroll
    for (int i = 0; i < 2; ++i)
      *((float4*)amS + i * 256 + t) = srcm[i * 256 + t];
  }

  const u16* kbase = qkv + (size_t)(b * SLEN) * LDQKV + DMODEL + h * DHEAD;
  const u16* vtbase = vT + (size_t)((b * NHEAD + h) * DHEAD) * SLEN;

#define STAGE(kt, buf)                                                              \
  {                                                                                 \
    _Pragma("unroll")                                                               \
    for (int p = 0; p < 2; ++p) {                                                   \
      const int idx = p * 256 + t;                                                  \
      const int row = idx >> 3;                                                     \
      const int blk = idx & 7;                                                      \
      const int sb = blk ^ (row & 7);                                               \
      gload_lds16(kbase + (size_t)((kt) * 64 + row) * LDQKV + sb * 8,               \
                  &Ks[buf][idx * 8]);                                               \
    }                                                                               \
    _Pragma("unroll")                                                               \
    for (int p = 0; p < 2; ++p) {                                                   \
      const int idx = p * 256 + t;                                                  \
      const int dh = idx >> 3;                                                      \
      const int blk = idx & 7;                                                      \
      const int sb = blk ^ (dh & 7);                                                \
      gload_lds16(vtbase + (size_t)dh * SLEN + (kt) * 64 + sb * 8,                  \
                  &Vs[buf][idx * 8]);                                               \
    }                                                                               \
  }

  f32x16 oA, oB;
#pragma unroll
  for (int r = 0; r < 16; ++r) { oA[r] = 0.f; oB[r] = 0.f; }
  float mrun = -3.0e38f, lsum = 0.f;

  STAGE(0, 0);
  asm volatile("s_waitcnt vmcnt(0)" ::: "memory");
  __syncthreads();

  int cur = 0;
  for (int kt = 0; kt < SLEN / 64; ++kt) {
    if (kt + 1 < SLEN / 64) STAGE(kt + 1, cur ^ 1);

    // ---- S^T = K . Q  (lane holds q = l31, kv rows in regs) ----
    f32x16 sA, sB;
#pragma unroll
    for (int r = 0; r < 16; ++r) { sA[r] = 0.f; sB[r] = 0.f; }
    __builtin_amdgcn_s_setprio(1);
#pragma unroll
    for (int f = 0; f < 4; ++f) {
      const int c = 2 * f + hi;
      s16x8 kA = *(const s16x8*)&Ks[cur][l31 * 64 + ((c ^ sw) & 7) * 8];
      s16x8 kB = *(const s16x8*)&Ks[cur][(32 + l31) * 64 + ((c ^ sw) & 7) * 8];
      sA = __builtin_amdgcn_mfma_f32_32x32x16_bf16(kA, qf[f], sA, 0, 0, 0);
      sB = __builtin_amdgcn_mfma_f32_32x32x16_bf16(kB, qf[f], sB, 0, 0, 0);
    }
    __builtin_amdgcn_s_setprio(0);

    const int kv0 = kt * 64;
    // mask add (LDS broadcast reads, uniform per half-wave)
#pragma unroll
    for (int r = 0; r < 16; ++r) {
      const int rid = (r & 3) + ((r >> 2) << 3) + hi4;
      sA[r] += amS[kv0 + rid];
      sB[r] += amS[kv0 + 32 + rid];
    }

    // row max over 64 kv: in-register tree + cross-half shfl
    float t8[8];
#pragma unroll
    for (int i = 0; i < 8; ++i)
      t8[i] = fmaxf(fmaxf(sA[2 * i], sA[2 * i + 1]), fmaxf(sB[2 * i], sB[2 * i + 1]));
#pragma unroll
    for (int i = 0; i < 4; ++i) t8[i] = fmaxf(t8[i], t8[i + 4]);
    t8[0] = fmaxf(t8[0], t8[2]); t8[1] = fmaxf(t8[1], t8[3]);
    float pm = fmaxf(t8[0], t8[1]);
    pm = fmaxf(pm, __shfl_xor(pm, 32));

    // exact online-softmax rescale (skip only when max did not grow)
    if (__any(pm > mrun)) {
      const float mnew = fmaxf(mrun, pm);
      const float alpha = __expf(mrun - mnew);
      mrun = mnew;
      lsum *= alpha;
      bcastS[w][l31] = alpha;
#pragma unroll
      for (int r = 0; r < 16; ++r) {
        const int rid = (r & 3) + ((r >> 2) << 3) + hi4;
        const float av = bcastS[w][rid];
        oA[r] *= av; oB[r] *= av;
      }
    }

    // exp + row sum
    float pA_[16], pB_[16];
#pragma unroll
    for (int r = 0; r < 16; ++r) {
      pA_[r] = __expf(sA[r] - mrun);
      pB_[r] = __expf(sB[r] - mrun);
    }
    float s8[8];
#pragma unroll
    for (int i = 0; i < 8; ++i)
      s8[i] = (pA_[2 * i] + pA_[2 * i + 1]) + (pB_[2 * i] + pB_[2 * i + 1]);
#pragma unroll
    for (int i = 0; i < 4; ++i) s8[i] += s8[i + 4];
    s8[0] += s8[2]; s8[1] += s8[3];
    float rsum = s8[0] + s8[1];
    rsum += __shfl_xor(rsum, 32);
    lsum += rsum;

    // P -> bf16 A-fragments (in-register, direction-proof exchange)
    s16x8 pa0 = make_pa(hi, pA_);
    s16x8 pa1 = make_pa(hi, pA_ + 8);
    s16x8 pa2 = make_pa(hi, pB_);
    s16x8 pa3 = make_pa(hi, pB_ + 8);

    // ---- O += P V ----
    __builtin_amdgcn_s_setprio(1);
#pragma unroll
    for (int s = 0; s < 4; ++s) {
      const int c = 2 * s + hi;
      s16x8 vA = *(const s16x8*)&Vs[cur][l31 * 64 + ((c ^ sw) & 7) * 8];
      s16x8 vB = *(const s16x8*)&Vs[cur][(32 + l31) * 64 + ((c ^ sw) & 7) * 8];
      const s16x8 pas = (s == 0) ? pa0 : (s == 1) ? pa1 : (s == 2) ? pa2 : pa3;
      oA = __builtin_amdgcn_mfma_f32_32x32x16_bf16(pas, vA, oA, 0, 0, 0);
      oB = __builtin_amdgcn_mfma_f32_32x32x16_bf16(pas, vB, oB, 0, 0, 0);
    }
    __builtin_amdgcn_s_setprio(0);

    asm volatile("s_waitcnt vmcnt(0)" ::: "memory");
    __syncthreads();
    cur ^= 1;
  }

  // epilogue: divide by lsum, write fp32
  bcastS[w][l31] = 1.0f / lsum;
  float* outp = out + (size_t)(b * SLEN + q0) * DMODEL + h * DHEAD + l31;
#pragma unroll
  for (int r = 0; r < 16; ++r) {
    const int rid = (r & 3) + ((r >> 2) << 3) + hi4;
    const float rv = bcastS[w][rid];
    outp[(size_t)rid * DMODEL] = oA[r] * rv;
    outp[(size_t)rid * DMODEL + 32] = oB[r] * rv;
  }
#undef STAGE
}

extern "C" void kernel_launch(void* const* d_in, const int* in_sizes, int n_in,
                              void* d_out, int out_size, void* d_ws, size_t ws_size,
                              hipStream_t stream) {
  const float* x    = (const float*)d_in[0];
  const float* mask = (const float*)d_in[1];
  const float* Wq   = (const float*)d_in[2];
  const float* bq   = (const float*)d_in[3];
  const float* Wk   = (const float*)d_in[4];
  const float* bk   = (const float*)d_in[5];
  const float* Wv   = (const float*)d_in[6];
  const float* bv   = (const float*)d_in[7];
  const float* Wo   = (const float*)d_in[8];
  const float* bo   = (const float*)d_in[9];
  const float* g1   = (const float*)d_in[10];
  const float* b1   = (const float*)d_in[11];
  const float* g2   = (const float*)d_in[12];
  const float* b2   = (const float*)d_in[13];
  float* out = (float*)d_out;
  char* ws = (char*)d_ws;

  u16*   h_bf  = (u16*)(ws + 0);                       // 8 MB
  u16*   Wqkv  = (u16*)(ws + ((size_t)8 << 20));       // 6 MB
  u16*   Wob   = (u16*)(ws + ((size_t)14 << 20));      // 2 MB
  float* biasq = (float*)(ws + ((size_t)16 << 20));    // 12 KB
  float* amv   = (float*)(ws + ((size_t)16 << 20) + (64 << 10));  // 16 KB
  u16*   qkv   = (u16*)(ws + ((size_t)17 << 20));      // 24 MB (later reused as resid)
  float* attn  = (float*)(ws + ((size_t)41 << 20));    // 16 MB
  float* resid = (float*)(ws + ((size_t)17 << 20));    // overlays dead qkv
  u16*   h2_bf = (u16*)(ws + 0);                       // overlays dead h_bf/vT
  u16*   vT    = (u16*)(ws + 0);                       // 8 MB, overlays dead h_bf

  convert_w_kernel<<<4096, 256, 0, stream>>>(Wq, Wk, Wv, Wo, bq, bk, bv, mask,
                                             Wqkv, Wob, biasq, amv);
  ln_kernel<false><<<4096, 256, 0, stream>>>(x, nullptr, g1, b1, h_bf, nullptr);
  gemm_bt_kernel<0><<<dim3(32, 24), 256, 0, stream>>>(h_bf, Wqkv, biasq, nullptr, qkv, nullptr,
                                                      4096, 3072, 1024);
  transpose_v_kernel<<<dim3(32, 16, 2), 256, 0, stream>>>(qkv, vT);
  attn_kernel<<<512, 256, 0, stream>>>(qkv, vT, amv, attn);
  ln_kernel<true><<<4096, 256, 0, stream>>>(attn, x, g2, b2, h2_bf, resid);
  gemm_bt_kernel<1><<<dim3(32, 8), 256, 0, stream>>>(h2_bf, Wob, bo, resid, nullptr, out,
                                                     4096, 1024, 1024);
}